// Round 11
// baseline (303.476 us; speedup 1.0000x reference)
//
#include <hip/hip_runtime.h>
#include <hip/hip_bf16.h>

typedef __attribute__((ext_vector_type(8))) short short8;
typedef __attribute__((ext_vector_type(4))) float f32x4;

#define MFMA16(a, b, c) __builtin_amdgcn_mfma_f32_16x16x32_bf16((a), (b), (c), 0, 0, 0)

#define BARRIER_V0() asm volatile("s_waitcnt vmcnt(0) lgkmcnt(0)\ns_barrier" ::: "memory")
#define BARRIER_V1() asm volatile("s_waitcnt vmcnt(1) lgkmcnt(0)\ns_barrier" ::: "memory")
#define BARRIER_LG() asm volatile("s_waitcnt lgkmcnt(0)\ns_barrier" ::: "memory")

__device__ __forceinline__ unsigned short f2bf(float x) {
    union { float f; unsigned int u; } v; v.f = x;
    unsigned int u = v.u;
    return (unsigned short)((u + 0x7FFFu + ((u >> 16) & 1u)) >> 16);
}

__device__ __forceinline__ float pow14(float x) {
    return exp2f(1.4f * log2f(x));
}

__device__ __forceinline__ short8 ld8(const unsigned short* p) {
    return *reinterpret_cast<const short8*>(p);
}

__device__ __forceinline__ void gld16(const unsigned short* src, unsigned char* dst) {
    __builtin_amdgcn_global_load_lds(
        (const __attribute__((address_space(1))) void*)src,
        (__attribute__((address_space(3))) void*)dst, 16, 0, 0);
}

// ---- K0: bbn fp32 -> bf16 (plain + row-swizzled copy), row sums s[i] ---------
__global__ void k_prep_bbn(const float* __restrict__ bbn, unsigned short* __restrict__ bbn_h,
                           unsigned short* __restrict__ bbn_swz, float* __restrict__ s) {
    int row = blockIdx.x * 4 + (threadIdx.x >> 6);
    int lane = threadIdx.x & 63;
    float x = bbn[row * 64 + lane];
    unsigned short h = f2bf(x);
    bbn_h[row * 64 + lane] = h;
    bbn_swz[row * 64 + (lane ^ ((row & 7) << 3))] = h;
    float v = x;
    #pragma unroll
    for (int m = 1; m < 64; m <<= 1) v += __shfl_xor(v, m);
    if (lane == 0) s[row] = v;
}

__global__ void k_zero_d(float* __restrict__ dd) {
    dd[blockIdx.x * 1024 + threadIdx.x] = 0.f;
}

// ---- K0b/K2: transpose (+optional rsqrt(d) row scale, optional swizzle) ------
__global__ void k_transpose_scale(const float* __restrict__ in, unsigned short* __restrict__ out,
                                  const float* __restrict__ dvec, int K, int N, int swz) {
    __shared__ float tile[64][65];
    int tiles_k = K >> 6;
    int tk = blockIdx.x % tiles_k, tn = blockIdx.x / tiles_k;
    int k0 = tk * 64, n0 = tn * 64;
    int c = threadIdx.x & 63, rq = threadIdx.x >> 6;
    #pragma unroll
    for (int i = 0; i < 16; ++i) {
        int r = rq + 4 * i;
        float sc = dvec ? rsqrtf(dvec[k0 + r]) : 1.0f;
        tile[r][c] = in[(size_t)(k0 + r) * N + n0 + c] * sc;
    }
    __syncthreads();
    #pragma unroll
    for (int i = 0; i < 16; ++i) {
        int r = rq + 4 * i;
        int cc = swz ? (c ^ ((r & 7) << 3)) : c;
        out[(size_t)(n0 + r) * K + k0 + cc] = f2bf(tile[c][r]);
    }
}

// ---- K1: materialize A (swizzled bf16) + degree d[i] --------------------------
// 512 blocks = 128 i-tiles x 4 j-quarters; 512 threads, 8 waves, 2 blocks/CU.
// Each wave gens two 16x16 subtiles (gi, gj2*2+p). Counted barrier vmcnt(1):
// Aj prefetch retired, A-writeback store left in flight (no store convoy).
__global__ __launch_bounds__(512, 4) void k_gen_adj(const unsigned short* __restrict__ bbn_h,
                                                    const unsigned short* __restrict__ bbn_swz,
                                                    const float* __restrict__ s,
                                                    unsigned short* __restrict__ A_swz,
                                                    float* __restrict__ dd) {
    int bx = blockIdx.x;
    int it = bx >> 2, jq = bx & 3;
    int i0 = it * 64, jbase = jq * 2048;

    int tid = threadIdx.x;
    int w = tid >> 6, l = tid & 63, g = l >> 4, c = l & 15;
    int gi = w & 3, gj2 = w >> 2;

    const unsigned short* ap = bbn_h + (i0 + gi * 16 + c) * 64;
    short8 ga0 = ld8(ap), ga1 = ld8(ap + 32);
    float si = s[i0 + gi * 16 + c];

    __shared__ unsigned char Ajlds[2][8192];
    __shared__ unsigned char Outlds[2][8192];

    // Aj staging: wave w covers rows [w*8, w*8+8) of the 64-row tile
    const unsigned short* ajbase = bbn_swz + (jbase + w * 8 + (l >> 3)) * 64 + (l & 7) * 8; // + t*4096
    const int ajdst = (w * 8) * 128;

    const int sw = (c & 7) << 4;
    const int gj0 = gj2 * 2, gj1 = gj2 * 2 + 1;
    const int bo00 = (gj0 * 16 + c) * 128 + ((g * 16) ^ sw);
    const int bo01 = (gj0 * 16 + c) * 128 + ((64 + g * 16) ^ sw);
    const int bo10 = (gj1 * 16 + c) * 128 + ((g * 16) ^ sw);
    const int bo11 = (gj1 * 16 + c) * 128 + ((64 + g * 16) ^ sw);
    const float* sb0 = s + jbase + gj0 * 16 + g * 4;  // + t*64
    const float* sb1 = s + jbase + gj1 * 16 + g * 4;
    const int wr0 = ((gi * 16 + c) * 128 + (gj0 * 16 + g * 4) * 2) ^ sw;
    const int wr1 = ((gi * 16 + c) * 128 + (gj1 * 16 + g * 4) * 2) ^ sw;

    float racc = 0.f;

#define GEN_TILE(T) do {                                                           \
    const unsigned char* aj = Ajlds[(T) & 1];                                      \
    _Pragma("unroll")                                                              \
    for (int p = 0; p < 2; ++p) {                                                  \
        short8 gb0 = *reinterpret_cast<const short8*>(&aj[p ? bo10 : bo00]);       \
        short8 gb1 = *reinterpret_cast<const short8*>(&aj[p ? bo11 : bo01]);       \
        f32x4 sj4 = *reinterpret_cast<const f32x4*>((p ? sb1 : sb0) + (T) * 64);   \
        f32x4 gf = {0.f, 0.f, 0.f, 0.f};                                           \
        gf = MFMA16(gb0, ga0, gf);                                                 \
        gf = MFMA16(gb1, ga1, gf);                                                 \
        float t0 = fmaf(2.f, gf[0], -(si + sj4[0]));                               \
        float t1 = fmaf(2.f, gf[1], -(si + sj4[1]));                               \
        float t2 = fmaf(2.f, gf[2], -(si + sj4[2]));                               \
        float t3 = fmaf(2.f, gf[3], -(si + sj4[3]));                               \
        float u0 = pow14(fmaxf(fmaf(fabsf(t0), -0.015625f, 1.f), 0.f));            \
        float u1 = pow14(fmaxf(fmaf(fabsf(t1), -0.015625f, 1.f), 0.f));            \
        float u2 = pow14(fmaxf(fmaf(fabsf(t2), -0.015625f, 1.f), 0.f));            \
        float u3 = pow14(fmaxf(fmaf(fabsf(t3), -0.015625f, 1.f), 0.f));            \
        racc += (u0 + u1) + (u2 + u3);                                             \
        unsigned short p0 = f2bf(u0), p1 = f2bf(u1), p2 = f2bf(u2), p3 = f2bf(u3); \
        *reinterpret_cast<uint2*>(&Outlds[(T) & 1][p ? wr1 : wr0]) =               \
            make_uint2((unsigned)p0 | ((unsigned)p1 << 16),                        \
                       (unsigned)p2 | ((unsigned)p3 << 16));                       \
    }                                                                              \
} while (0)

    // prologue
    gld16(ajbase, &Ajlds[0][ajdst]);
    BARRIER_V0();

    for (int t = 0; t < 32; ++t) {
        if (t < 31) gld16(ajbase + (t + 1) * 4096, &Ajlds[(t + 1) & 1][ajdst]);
        GEN_TILE(t);
        if (t > 0) {
            int row = tid >> 3, seg = tid & 7;
            uint4 v = *reinterpret_cast<const uint4*>(&Outlds[(t - 1) & 1][tid * 16]);
            *reinterpret_cast<uint4*>(A_swz + (size_t)(i0 + row) * 8192 + jbase + (t - 1) * 64 + seg * 8) = v;
        }
        if (t == 0) { BARRIER_V0(); } else { BARRIER_V1(); }
    }
    // final tile writeback
    {
        int row = tid >> 3, seg = tid & 7;
        uint4 v = *reinterpret_cast<const uint4*>(&Outlds[1][tid * 16]);
        *reinterpret_cast<uint4*>(A_swz + (size_t)(i0 + row) * 8192 + jbase + 31 * 64 + seg * 8) = v;
    }
#undef GEN_TILE

    // degree: reduce over g-groups, atomic per (gi, c)
    racc += __shfl_xor(racc, 16);
    racc += __shfl_xor(racc, 32);
    if (g == 0) atomicAdd(&dd[i0 + gi * 16 + c], racc);
}

// ---- K3: GEMM h = A_swz @ cbn_sT^T, 64x64 per wave ----------------------------
// BM=BN=128, BK=64; 256 threads, 4 waves (2x2). Grid 256 = 64 row x 4 col tiles,
// 2 blocks/CU. LDS 64KB dbuf. 16 ds_read_b128 + 32 MFMA per wave per iter
// (16 MAC/B vs r10's 8 — halves the LDS-read amplification that bound r10).
__global__ __launch_bounds__(256, 2) void k_spectral(const unsigned short* __restrict__ A_swz,
                                                     const float* __restrict__ d,
                                                     const unsigned short* __restrict__ cbn_sT,
                                                     unsigned short* __restrict__ h) {
    int bx = blockIdx.x;
    int xcd = bx & 7, grp = bx >> 3;
    int n0 = (xcd >> 1) * 128;               // 2 XCDs per col-tile (2MB B slab in L2)
    int i0 = (grp * 2 + (xcd & 1)) * 128;    // 64 row-tiles

    int tid = threadIdx.x;
    int w = tid >> 6, l = tid & 63, g = l >> 4, c = l & 15;
    int wm = w >> 1, wn = w & 1;
    int lrow = l >> 3, lseg = l & 7;

    __shared__ unsigned char Alds[2][16384];
    __shared__ unsigned char Blds[2][16384];

    f32x4 acc[4][4] = {};

    const unsigned short* srcA = A_swz + (size_t)(i0 + w * 8 + lrow) * 8192 + lseg * 8;
    const unsigned short* srcB = cbn_sT + (size_t)(n0 + w * 8 + lrow) * 8192 + lseg * 8;
    const int sw = (c & 7) << 4;

#define STAGE(BUF, JT) do {                                                        \
    _Pragma("unroll")                                                              \
    for (int r = 0; r < 4; ++r)                                                    \
        gld16(srcA + (size_t)(r * 32) * 8192 + (JT), &Alds[BUF][(w * 8 + r * 32) * 128]); \
    _Pragma("unroll")                                                              \
    for (int r = 0; r < 4; ++r)                                                    \
        gld16(srcB + (size_t)(r * 32) * 8192 + (JT), &Blds[BUF][(w * 8 + r * 32) * 128]); \
} while (0)

    STAGE(0, 0);
    BARRIER_V0();

    for (int t = 0; t < 128; ++t) {
        int cur = t & 1, nxt = cur ^ 1;
        if (t < 127) STAGE(nxt, (t + 1) * 64);

        short8 af[4][2], bf[2][4];
        #pragma unroll
        for (int mi = 0; mi < 4; ++mi)
            #pragma unroll
            for (int kk = 0; kk < 2; ++kk)
                af[mi][kk] = *reinterpret_cast<const short8*>(
                    &Alds[cur][(wm * 64 + mi * 16 + c) * 128 + ((kk * 64 + g * 16) ^ sw)]);
        #pragma unroll
        for (int kk = 0; kk < 2; ++kk)
            #pragma unroll
            for (int nn = 0; nn < 4; ++nn)
                bf[kk][nn] = *reinterpret_cast<const short8*>(
                    &Blds[cur][(wn * 64 + nn * 16 + c) * 128 + ((kk * 64 + g * 16) ^ sw)]);

        __builtin_amdgcn_s_setprio(1);
        #pragma unroll
        for (int kk = 0; kk < 2; ++kk)
            #pragma unroll
            for (int mi = 0; mi < 4; ++mi)
                #pragma unroll
                for (int nn = 0; nn < 4; ++nn)
                    acc[mi][nn] = MFMA16(af[mi][kk], bf[kk][nn], acc[mi][nn]);
        __builtin_amdgcn_s_setprio(0);
        BARRIER_V0();
    }
#undef STAGE

    // epilogue: scale by dinv_i, store bf16 h
    #pragma unroll
    for (int mi = 0; mi < 4; ++mi) {
        f32x4 d4 = *reinterpret_cast<const f32x4*>(d + i0 + wm * 64 + mi * 16 + g * 4);
        #pragma unroll
        for (int r = 0; r < 4; ++r) {
            int row = i0 + wm * 64 + mi * 16 + g * 4 + r;
            float dinv = rsqrtf(d4[r]);
            #pragma unroll
            for (int nn = 0; nn < 4; ++nn)
                h[(size_t)row * 512 + n0 + wn * 64 + nn * 16 + c] = f2bf(acc[mi][nn][r] * dinv);
        }
    }
}

// ---- K4: out = sigmoid(h @ W + b), fp32 out ----------------------------------
__global__ __launch_bounds__(512) void k_out(const unsigned short* __restrict__ h,
                                             const unsigned short* __restrict__ Wt,
                                             const float* __restrict__ b,
                                             float* __restrict__ out) {
    int bx = blockIdx.x;
    int i0 = (bx & 255) * 32, n0 = (bx >> 8) * 256;
    int tid = threadIdx.x;
    int w = tid >> 6, l = tid & 63, g = l >> 4, c = l & 15;
    int wm = w >> 2, wn = w & 3;

    float bb[4];
    #pragma unroll
    for (int nn = 0; nn < 4; ++nn) bb[nn] = b[n0 + wn * 64 + nn * 16 + c];

    f32x4 acc[4] = {};
    for (int k0 = 0; k0 < 512; k0 += 64) {
        short8 af[2];
        #pragma unroll
        for (int kk = 0; kk < 2; ++kk)
            af[kk] = ld8(h + (size_t)(i0 + wm * 16 + c) * 512 + k0 + kk * 32 + g * 8);
        #pragma unroll
        for (int kk = 0; kk < 2; ++kk)
            #pragma unroll
            for (int nn = 0; nn < 4; ++nn) {
                short8 bf = ld8(Wt + (size_t)(n0 + wn * 64 + nn * 16 + c) * 512 + k0 + kk * 32 + g * 8);
                acc[nn] = MFMA16(af[kk], bf, acc[nn]);
            }
    }
    #pragma unroll
    for (int r = 0; r < 4; ++r) {
        int row = i0 + wm * 16 + g * 4 + r;
        #pragma unroll
        for (int nn = 0; nn < 4; ++nn) {
            float z = acc[nn][r] + bb[nn];
            out[(size_t)row * 512 + n0 + wn * 64 + nn * 16 + c] = 1.f / (1.f + exp2f(-1.44269504f * z));
        }
    }
}

extern "C" void kernel_launch(void* const* d_in, const int* in_sizes, int n_in,
                              void* d_out, int out_size, void* d_ws, size_t ws_size,
                              hipStream_t stream) {
    const float* bbn = (const float*)d_in[0];   // [8192, 64]
    const float* cbn = (const float*)d_in[1];   // [8192, 512]
    const float* W   = (const float*)d_in[2];   // [512, 512]
    const float* b   = (const float*)d_in[3];   // [512]
    float* out = (float*)d_out;                 // [8192, 512] fp32

    char* ws = (char*)d_ws;
    unsigned short* bbn_h   = (unsigned short*)(ws);                    // 1 MB
    unsigned short* bbn_swz = (unsigned short*)(ws + (1u << 20));       // 1 MB
    float*          s       = (float*)(ws + (2u << 20));                // 32 KB
    float*          dd      = (float*)(ws + (2u << 20) + (1u << 15));   // 32 KB
    unsigned short* Wt      = (unsigned short*)(ws + (2u << 20) + (2u << 15));  // 512 KB
    unsigned short* cbn_sT  = (unsigned short*)(ws + (3u << 20));       // 8 MB (swizzled, dinv_j-scaled)
    unsigned short* hbuf    = (unsigned short*)(ws + (11u << 20));      // 8 MB
    unsigned short* A_swz   = (unsigned short*)(ws + (19u << 20));      // 128 MB (swizzled adjacency)

    k_prep_bbn<<<2048, 256, 0, stream>>>(bbn, bbn_h, bbn_swz, s);
    k_zero_d<<<8, 1024, 0, stream>>>(dd);
    k_transpose_scale<<<64, 256, 0, stream>>>(W, Wt, nullptr, 512, 512, 0);
    k_gen_adj<<<512, 512, 0, stream>>>(bbn_h, bbn_swz, s, A_swz, dd);
    k_transpose_scale<<<1024, 256, 0, stream>>>(cbn, cbn_sT, dd, 8192, 512, 1);
    k_spectral<<<256, 256, 0, stream>>>(A_swz, dd, cbn_sT, hbuf);
    k_out<<<512, 512, 0, stream>>>(hbuf, Wt, b, out);
}

// Round 12
// 257.999 us; speedup vs baseline: 1.1763x; 1.1763x over previous
//
#include <hip/hip_runtime.h>
#include <hip/hip_bf16.h>

typedef __attribute__((ext_vector_type(8))) short short8;
typedef __attribute__((ext_vector_type(4))) float f32x4;

#define MFMA16(a, b, c) __builtin_amdgcn_mfma_f32_16x16x32_bf16((a), (b), (c), 0, 0, 0)

__device__ __forceinline__ unsigned short f2bf(float x) {
    union { float f; unsigned int u; } v; v.f = x;
    unsigned int u = v.u;
    return (unsigned short)((u + 0x7FFFu + ((u >> 16) & 1u)) >> 16);
}

__device__ __forceinline__ float pow14(float x) {
    return exp2f(1.4f * log2f(x));
}

__device__ __forceinline__ short8 ld8(const unsigned short* p) {
    return *reinterpret_cast<const short8*>(p);
}

__device__ __forceinline__ void gld16(const void* src, const unsigned char* dst) {
    __builtin_amdgcn_global_load_lds(
        (const __attribute__((address_space(1))) void*)src,
        (__attribute__((address_space(3))) void*)dst, 16, 0, 0);
}

// ---- K0: bbn fp32 -> bf16 (plain + row-swizzled copy), row sums s[i] ---------
__global__ void k_prep_bbn(const float* __restrict__ bbn, unsigned short* __restrict__ bbn_h,
                           unsigned short* __restrict__ bbn_swz, float* __restrict__ s) {
    int row = blockIdx.x * 4 + (threadIdx.x >> 6);
    int lane = threadIdx.x & 63;
    float x = bbn[row * 64 + lane];
    unsigned short h = f2bf(x);
    bbn_h[row * 64 + lane] = h;
    bbn_swz[row * 64 + (lane ^ ((row & 7) << 3))] = h;
    float v = x;
    #pragma unroll
    for (int m = 1; m < 64; m <<= 1) v += __shfl_xor(v, m);
    if (lane == 0) s[row] = v;
}

__global__ void k_zero_d(float* __restrict__ dd) {
    dd[blockIdx.x * 1024 + threadIdx.x] = 0.f;
}

// ---- K0b/K2: transpose (+optional rsqrt(d) row scale, optional swizzle) ------
__global__ void k_transpose_scale(const float* __restrict__ in, unsigned short* __restrict__ out,
                                  const float* __restrict__ dvec, int K, int N, int swz) {
    __shared__ float tile[64][65];
    int tiles_k = K >> 6;
    int tk = blockIdx.x % tiles_k, tn = blockIdx.x / tiles_k;
    int k0 = tk * 64, n0 = tn * 64;
    int c = threadIdx.x & 63, rq = threadIdx.x >> 6;
    #pragma unroll
    for (int i = 0; i < 16; ++i) {
        int r = rq + 4 * i;
        float sc = dvec ? rsqrtf(dvec[k0 + r]) : 1.0f;
        tile[r][c] = in[(size_t)(k0 + r) * N + n0 + c] * sc;
    }
    __syncthreads();
    #pragma unroll
    for (int i = 0; i < 16; ++i) {
        int r = rq + 4 * i;
        int cc = swz ? (c ^ ((r & 7) << 3)) : c;
        out[(size_t)(n0 + r) * K + k0 + cc] = f2bf(tile[c][r]);
    }
}

// ---- K1: materialize A (swizzled bf16) + degree d[i] --------------------------
// 512 blocks = 128 i-tiles x 4 j-quarters; 512 threads, 8 waves, 2 blocks/CU.
// Triple-buffered Aj staged for t+2; s-quarter in LDS (no per-iter global sj
// loads -> no compiler-injected vmcnt drains); counted barrier vmcnt(2) leaves
// {A-writeback store, Aj(t+2) gld} in flight while retiring Aj(t+1).
__global__ __launch_bounds__(512, 4) void k_gen_adj(const unsigned short* __restrict__ bbn_h,
                                                    const unsigned short* __restrict__ bbn_swz,
                                                    const float* __restrict__ s,
                                                    unsigned short* __restrict__ A_swz,
                                                    float* __restrict__ dd) {
    int bx = blockIdx.x;
    int it = bx >> 2, jq = bx & 3;
    int i0 = it * 64, jbase = jq * 2048;

    int tid = threadIdx.x;
    int w = tid >> 6, l = tid & 63, g = l >> 4, c = l & 15;
    int gi = w & 3, gj2 = w >> 2;

    const unsigned short* ap = bbn_h + (i0 + gi * 16 + c) * 64;
    short8 ga0 = ld8(ap), ga1 = ld8(ap + 32);
    float si = s[i0 + gi * 16 + c];

    __shared__ unsigned char AjldsF[3 * 8192];
    __shared__ unsigned char OutldsF[2 * 8192];
    __shared__ float sLDS[2048];

    const unsigned short* ajbase = bbn_swz + (jbase + w * 8 + (l >> 3)) * 64 + (l & 7) * 8;
    const int ajdst = w * 1024;

    const int sw = (c & 7) << 4;
    const int gj0 = gj2 * 2, gj1 = gj2 * 2 + 1;
    const int bo00 = (gj0 * 16 + c) * 128 + ((g * 16) ^ sw);
    const int bo01 = (gj0 * 16 + c) * 128 + ((64 + g * 16) ^ sw);
    const int bo10 = (gj1 * 16 + c) * 128 + ((g * 16) ^ sw);
    const int bo11 = (gj1 * 16 + c) * 128 + ((64 + g * 16) ^ sw);
    const int wr0 = ((gi * 16 + c) * 128 + (gj0 * 16 + g * 4) * 2) ^ sw;
    const int wr1 = ((gi * 16 + c) * 128 + (gj1 * 16 + g * 4) * 2) ^ sw;

    float racc = 0.f;

#define GEN_TILE(T) do {                                                           \
    const unsigned char* aj = &AjldsF[((T) % 3) * 8192];                           \
    unsigned char* outp = &OutldsF[((T) & 1) * 8192];                              \
    _Pragma("unroll")                                                              \
    for (int p = 0; p < 2; ++p) {                                                  \
        short8 gb0 = *reinterpret_cast<const short8*>(&aj[p ? bo10 : bo00]);       \
        short8 gb1 = *reinterpret_cast<const short8*>(&aj[p ? bo11 : bo01]);       \
        f32x4 sj4 = *reinterpret_cast<const f32x4*>(                               \
            &sLDS[(T) * 64 + (p ? gj1 : gj0) * 16 + g * 4]);                       \
        f32x4 gf = {0.f, 0.f, 0.f, 0.f};                                           \
        gf = MFMA16(gb0, ga0, gf);                                                 \
        gf = MFMA16(gb1, ga1, gf);                                                 \
        float t0 = fmaf(2.f, gf[0], -(si + sj4[0]));                               \
        float t1 = fmaf(2.f, gf[1], -(si + sj4[1]));                               \
        float t2 = fmaf(2.f, gf[2], -(si + sj4[2]));                               \
        float t3 = fmaf(2.f, gf[3], -(si + sj4[3]));                               \
        float u0 = pow14(fmaxf(fmaf(fabsf(t0), -0.015625f, 1.f), 0.f));            \
        float u1 = pow14(fmaxf(fmaf(fabsf(t1), -0.015625f, 1.f), 0.f));            \
        float u2 = pow14(fmaxf(fmaf(fabsf(t2), -0.015625f, 1.f), 0.f));            \
        float u3 = pow14(fmaxf(fmaf(fabsf(t3), -0.015625f, 1.f), 0.f));            \
        racc += (u0 + u1) + (u2 + u3);                                             \
        unsigned short p0 = f2bf(u0), p1 = f2bf(u1), p2 = f2bf(u2), p3 = f2bf(u3); \
        *reinterpret_cast<uint2*>(&outp[p ? wr1 : wr0]) =                          \
            make_uint2((unsigned)p0 | ((unsigned)p1 << 16),                        \
                       (unsigned)p2 | ((unsigned)p3 << 16));                       \
    }                                                                              \
} while (0)

    // prologue: s-quarter -> LDS, Aj(0), Aj(1)
    gld16(s + jbase + w * 256 + l * 4, (unsigned char*)sLDS + w * 1024);
    gld16(ajbase, &AjldsF[ajdst]);
    gld16(ajbase + 4096, &AjldsF[8192 + ajdst]);
    asm volatile("s_waitcnt vmcnt(1) lgkmcnt(0)\ns_barrier" ::: "memory");

    for (int t = 0; t < 32; ++t) {
        if (t > 0) {   // writeback tile t-1 (store left in flight by vmcnt(2))
            int row = tid >> 3, seg = tid & 7;
            uint4 v = *reinterpret_cast<const uint4*>(&OutldsF[((t - 1) & 1) * 8192 + tid * 16]);
            *reinterpret_cast<uint4*>(A_swz + (size_t)(i0 + row) * 8192 + jbase + (t - 1) * 64 + seg * 8) = v;
        }
        int jt = (t + 2 < 32) ? t + 2 : 31;
        gld16(ajbase + jt * 4096, &AjldsF[((t + 2) % 3) * 8192 + ajdst]);
        GEN_TILE(t);
        if (t == 0) { asm volatile("s_waitcnt vmcnt(1) lgkmcnt(0)\ns_barrier" ::: "memory"); }
        else        { asm volatile("s_waitcnt vmcnt(2) lgkmcnt(0)\ns_barrier" ::: "memory"); }
    }
    {   // final tile writeback
        int row = tid >> 3, seg = tid & 7;
        uint4 v = *reinterpret_cast<const uint4*>(&OutldsF[(31 & 1) * 8192 + tid * 16]);
        *reinterpret_cast<uint4*>(A_swz + (size_t)(i0 + row) * 8192 + jbase + 31 * 64 + seg * 8) = v;
    }
#undef GEN_TILE

    racc += __shfl_xor(racc, 16);
    racc += __shfl_xor(racc, 32);
    if (g == 0) atomicAdd(&dd[i0 + gi * 16 + c], racc);
}

// ---- K3: GEMM h = A_swz @ cbn_sT^T ------------------------------------------
// BM=64, BN=256, BK=64; 512 threads, 8 waves (2x4), wave tile 32x64.
// Grid 256 = 128 row-tiles x 2 col-halves (XCD-pinned 4MB B slab).
// Triple-buffered, stage t+2, uniform vmcnt(5) (5 gld16/wave/iter) -> t+1's
// stage is retired while t+2's stays in flight; no other loop VMEM.
__global__ __launch_bounds__(512, 2) void k_spectral(const unsigned short* __restrict__ A_swz,
                                                     const float* __restrict__ d,
                                                     const unsigned short* __restrict__ cbn_sT,
                                                     unsigned short* __restrict__ h) {
    int bx = blockIdx.x;
    int i0 = (bx >> 1) * 64;
    int n0 = (bx & 1) * 256;

    int tid = threadIdx.x;
    int w = tid >> 6, l = tid & 63, g = l >> 4, c = l & 15;
    int wm = w >> 2, wn = w & 3;     // wave tile: rows wm*32, cols wn*64
    int lrow = l >> 3, lseg = l & 7;

    __shared__ unsigned char AldsF[3 * 8192];
    __shared__ unsigned char BldsF[3 * 32768];

    f32x4 acc[2][4] = {};

    const unsigned short* srcA = A_swz + (size_t)(i0 + w * 8 + lrow) * 8192 + lseg * 8;
    const unsigned short* srcB = cbn_sT + (size_t)(n0 + w * 32 + lrow) * 8192 + lseg * 8;
    const int sw = (c & 7) << 4;

#define STAGE(BUF, JT) do {                                                        \
    gld16(srcA + (JT), &AldsF[(BUF) * 8192 + w * 1024]);                           \
    _Pragma("unroll")                                                              \
    for (int q = 0; q < 4; ++q)                                                    \
        gld16(srcB + (size_t)(q * 8) * 8192 + (JT),                                \
              &BldsF[(BUF) * 32768 + (w * 32 + q * 8) * 128]);                     \
} while (0)

    STAGE(0, 0);
    STAGE(1, 64);
    asm volatile("s_waitcnt vmcnt(5) lgkmcnt(0)\ns_barrier" ::: "memory");

    for (int t = 0; t < 128; ++t) {
        int jt = ((t + 2 < 128) ? t + 2 : 127) * 64;
        STAGE((t + 2) % 3, jt);

        const unsigned char* Ab = &AldsF[(t % 3) * 8192];
        const unsigned char* Bb = &BldsF[(t % 3) * 32768];
        short8 af[2][2], bf[2][4];
        #pragma unroll
        for (int mi = 0; mi < 2; ++mi)
            #pragma unroll
            for (int kk = 0; kk < 2; ++kk)
                af[mi][kk] = *reinterpret_cast<const short8*>(
                    &Ab[(wm * 32 + mi * 16 + c) * 128 + ((kk * 64 + g * 16) ^ sw)]);
        #pragma unroll
        for (int kk = 0; kk < 2; ++kk)
            #pragma unroll
            for (int nn = 0; nn < 4; ++nn)
                bf[kk][nn] = *reinterpret_cast<const short8*>(
                    &Bb[(wn * 64 + nn * 16 + c) * 128 + ((kk * 64 + g * 16) ^ sw)]);

        __builtin_amdgcn_s_setprio(1);
        #pragma unroll
        for (int kk = 0; kk < 2; ++kk)
            #pragma unroll
            for (int nn = 0; nn < 4; ++nn) {
                acc[0][nn] = MFMA16(af[0][kk], bf[kk][nn], acc[0][nn]);
                acc[1][nn] = MFMA16(af[1][kk], bf[kk][nn], acc[1][nn]);
            }
        __builtin_amdgcn_s_setprio(0);
        asm volatile("s_waitcnt vmcnt(5) lgkmcnt(0)\ns_barrier" ::: "memory");
    }
#undef STAGE

    // epilogue: scale by dinv_i, store bf16 h
    #pragma unroll
    for (int mi = 0; mi < 2; ++mi) {
        f32x4 d4 = *reinterpret_cast<const f32x4*>(d + i0 + wm * 32 + mi * 16 + g * 4);
        #pragma unroll
        for (int r = 0; r < 4; ++r) {
            int row = i0 + wm * 32 + mi * 16 + g * 4 + r;
            float dinv = rsqrtf(d4[r]);
            #pragma unroll
            for (int nn = 0; nn < 4; ++nn)
                h[(size_t)row * 512 + n0 + wn * 64 + nn * 16 + c] = f2bf(acc[mi][nn][r] * dinv);
        }
    }
}

// ---- K4: out = sigmoid(h @ W + b), fp32 out ----------------------------------
__global__ __launch_bounds__(512) void k_out(const unsigned short* __restrict__ h,
                                             const unsigned short* __restrict__ Wt,
                                             const float* __restrict__ b,
                                             float* __restrict__ out) {
    int bx = blockIdx.x;
    int i0 = (bx & 255) * 32, n0 = (bx >> 8) * 256;
    int tid = threadIdx.x;
    int w = tid >> 6, l = tid & 63, g = l >> 4, c = l & 15;
    int wm = w >> 2, wn = w & 3;

    float bb[4];
    #pragma unroll
    for (int nn = 0; nn < 4; ++nn) bb[nn] = b[n0 + wn * 64 + nn * 16 + c];

    f32x4 acc[4] = {};
    for (int k0 = 0; k0 < 512; k0 += 64) {
        short8 af[2];
        #pragma unroll
        for (int kk = 0; kk < 2; ++kk)
            af[kk] = ld8(h + (size_t)(i0 + wm * 16 + c) * 512 + k0 + kk * 32 + g * 8);
        #pragma unroll
        for (int kk = 0; kk < 2; ++kk)
            #pragma unroll
            for (int nn = 0; nn < 4; ++nn) {
                short8 bf = ld8(Wt + (size_t)(n0 + wn * 64 + nn * 16 + c) * 512 + k0 + kk * 32 + g * 8);
                acc[nn] = MFMA16(af[kk], bf, acc[nn]);
            }
    }
    #pragma unroll
    for (int r = 0; r < 4; ++r) {
        int row = i0 + wm * 16 + g * 4 + r;
        #pragma unroll
        for (int nn = 0; nn < 4; ++nn) {
            float z = acc[nn][r] + bb[nn];
            out[(size_t)row * 512 + n0 + wn * 64 + nn * 16 + c] = 1.f / (1.f + exp2f(-1.44269504f * z));
        }
    }
}

extern "C" void kernel_launch(void* const* d_in, const int* in_sizes, int n_in,
                              void* d_out, int out_size, void* d_ws, size_t ws_size,
                              hipStream_t stream) {
    const float* bbn = (const float*)d_in[0];   // [8192, 64]
    const float* cbn = (const float*)d_in[1];   // [8192, 512]
    const float* W   = (const float*)d_in[2];   // [512, 512]
    const float* b   = (const float*)d_in[3];   // [512]
    float* out = (float*)d_out;                 // [8192, 512] fp32

    char* ws = (char*)d_ws;
    unsigned short* bbn_h   = (unsigned short*)(ws);                    // 1 MB
    unsigned short* bbn_swz = (unsigned short*)(ws + (1u << 20));       // 1 MB
    float*          s       = (float*)(ws + (2u << 20));                // 32 KB
    float*          dd      = (float*)(ws + (2u << 20) + (1u << 15));   // 32 KB
    unsigned short* Wt      = (unsigned short*)(ws + (2u << 20) + (2u << 15));  // 512 KB
    unsigned short* cbn_sT  = (unsigned short*)(ws + (3u << 20));       // 8 MB (swizzled, dinv_j-scaled)
    unsigned short* hbuf    = (unsigned short*)(ws + (11u << 20));      // 8 MB
    unsigned short* A_swz   = (unsigned short*)(ws + (19u << 20));      // 128 MB (swizzled adjacency)

    k_prep_bbn<<<2048, 256, 0, stream>>>(bbn, bbn_h, bbn_swz, s);
    k_zero_d<<<8, 1024, 0, stream>>>(dd);
    k_transpose_scale<<<64, 256, 0, stream>>>(W, Wt, nullptr, 512, 512, 0);
    k_gen_adj<<<512, 512, 0, stream>>>(bbn_h, bbn_swz, s, A_swz, dd);
    k_transpose_scale<<<1024, 256, 0, stream>>>(cbn, cbn_sT, dd, 8192, 512, 1);
    k_spectral<<<256, 512, 0, stream>>>(A_swz, dd, cbn_sT, hbuf);
    k_out<<<512, 512, 0, stream>>>(hbuf, Wt, b, out);
}